// Round 3
// baseline (117.089 us; speedup 1.0000x reference)
//
#include <hip/hip_runtime.h>

// QuantumMeasurement: exp[b,q] = sum_i (re^2+im^2)[b,i] * (-1)^{bit_{9-q}(i)}
// Pauli-Z is diagonal: never read the 80 MB observable. Pure streaming
// reduction, 64 MB in, 320 KB out. One 64-lane wave per batch row.
// Grid is fully co-resident (2048 blocks = 256 CU x 8 blocks/CU), so the
// epilogue overlaps other waves' loads and is off the critical path (proven
// by v1->v2 null). v3 attacks the only remaining lever: the load stream.
//
// v3 changes vs v2 (112.16 us):
//  - nontemporal loads (global_load_dwordx4 ... nt): single-use stream,
//    skip L2 allocation (L2 is full of dirty poison-fill lines when we run)
//  - R/I interleaved issue order: first ACC depends on the two OLDEST loads
//    (vmcnt(6) at first use instead of vmcnt(3))
//  - (fix vs failed compile: __builtin_nontemporal_load needs a clang
//    ext_vector_type pointer, not HIP_vector_type float4*)

#define BATCH 8192
#define DIM   1024
#define NQ    10

typedef float v4f __attribute__((ext_vector_type(4)));

__global__ __launch_bounds__(256, 8) void qmeas_kernel(
    const float* __restrict__ sre,
    const float* __restrict__ sim,
    float* __restrict__ out)
{
    const int row  = (int)((blockIdx.x * blockDim.x + threadIdx.x) >> 6);
    const int lane = (int)(threadIdx.x & 63);
    const int wv   = (int)(threadIdx.x >> 6);   // wave id within block (0..3)

    const v4f* __restrict__ rowR = (const v4f*)(sre + (size_t)row * DIM);
    const v4f* __restrict__ rowI = (const v4f*)(sim + (size_t)row * DIM);

    // element index i = 4*(lane + 64*it) + c
    //   bits 0,1 of i = c     -> qubits 9,8  (intra-float4 signed combos)
    //   bits 2..7 of i = lane -> qubits 7..2 (signed WHT butterfly)
    //   bits 8,9 of i = it    -> qubits 1,0  (compile-time signs)

    // 8 nontemporal loads, R/I interleaved, all in flight before first use
    v4f r0 = __builtin_nontemporal_load(rowR + lane);
    v4f m0 = __builtin_nontemporal_load(rowI + lane);
    v4f r1 = __builtin_nontemporal_load(rowR + lane + 64);
    v4f m1 = __builtin_nontemporal_load(rowI + lane + 64);
    v4f r2 = __builtin_nontemporal_load(rowR + lane + 128);
    v4f m2 = __builtin_nontemporal_load(rowI + lane + 128);
    v4f r3 = __builtin_nontemporal_load(rowR + lane + 192);
    v4f m3 = __builtin_nontemporal_load(rowI + lane + 192);

    float tot = 0.f, a8 = 0.f, a9 = 0.f, aq0 = 0.f, aq1 = 0.f;

#define ACC(rr, mm, it) do {                                    \
        float p0 = fmaf(rr.x, rr.x, mm.x * mm.x);               \
        float p1 = fmaf(rr.y, rr.y, mm.y * mm.y);               \
        float p2 = fmaf(rr.z, rr.z, mm.z * mm.z);               \
        float p3 = fmaf(rr.w, rr.w, mm.w * mm.w);               \
        float pa = p0 + p1, pb = p2 + p3;                       \
        float pe = p0 - p1, pf = p2 - p3;                       \
        float ps = pa + pb;                                     \
        a9  += pe + pf;              /* qubit 9: bit0 of i */   \
        a8  += pa - pb;              /* qubit 8: bit1 of i */   \
        tot += ps;                                              \
        aq1 += ((it) & 1) ? -ps : ps; /* qubit 1: bit8 of i */  \
        aq0 += ((it) & 2) ? -ps : ps; /* qubit 0: bit9 of i */  \
    } while (0)

    ACC(r0, m0, 0);
    ACC(r1, m1, 1);
    ACC(r2, m2, 2);
    ACC(r3, m3, 3);
#undef ACC

    // ---- signed Walsh-Hadamard butterfly on tot (6 shuffles total) ----
    // After all 6 levels, lane L = 1<<k holds sum_j (-1)^{bit_k(j)} tot_j,
    // i.e. qubit 7-k (lane bit k is bit k+2 of element index i).
    float s = tot;
#pragma unroll
    for (int k = 0; k < 6; ++k) {
        float y = __shfl_xor(s, 1 << k);
        s = (lane & (1 << k)) ? (y - s) : (s + y);
    }

    // ---- LDS transpose for the 4 plain sums (aq0, aq1, a8, a9) ----
    // write: ds_write_b128, conflict-free (lanes 0..7 cover all 32 banks).
    // read: 16-lane group g sums accumulator g; 2-way aliasing only (free).
    __shared__ float xp[4][64][4];
    xp[wv][lane][0] = aq0;
    xp[wv][lane][1] = aq1;
    xp[wv][lane][2] = a8;
    xp[wv][lane][3] = a9;
    __syncthreads();

    const int g = lane >> 4;      // which accumulator this group reduces
    const int m = lane & 15;
    float v0 = xp[wv][m     ][g];
    float v1 = xp[wv][m + 16][g];
    float v2 = xp[wv][m + 32][g];
    float v3 = xp[wv][m + 48][g];
    float sum4 = (v0 + v1) + (v2 + v3);
#pragma unroll
    for (int d = 1; d < 16; d <<= 1)   // stays within the 16-lane group
        sum4 += __shfl_xor(sum4, d);

    // ---- one predicated wave store: 10 lanes write 10 contiguous floats --
    // WHT lanes 1,2,4,8,16,32 -> qubits 7,6,5,4,3,2
    // group reps 3,19,35,51   -> qubits 0,1,8,9 (avoid WHT lanes)
    int   q   = -1;
    float val = 0.f;
    if      (lane == 1)  { q = 7; val = s; }
    else if (lane == 2)  { q = 6; val = s; }
    else if (lane == 4)  { q = 5; val = s; }
    else if (lane == 8)  { q = 4; val = s; }
    else if (lane == 16) { q = 3; val = s; }
    else if (lane == 32) { q = 2; val = s; }
    else if (lane == 3)  { q = 0; val = sum4; }
    else if (lane == 19) { q = 1; val = sum4; }
    else if (lane == 35) { q = 8; val = sum4; }
    else if (lane == 51) { q = 9; val = sum4; }
    if (q >= 0)
        out[(size_t)row * NQ + q] = val;
}

extern "C" void kernel_launch(void* const* d_in, const int* in_sizes, int n_in,
                              void* d_out, int out_size, void* d_ws, size_t ws_size,
                              hipStream_t stream) {
    const float* sre = (const float*)d_in[0];
    const float* sim = (const float*)d_in[1];
    // d_in[2] (pauli_z_obs) intentionally unused: diagonal signs are analytic.
    float* out = (float*)d_out;

    dim3 grid(BATCH / 4), block(256);   // 4 waves (rows) per block, 8192 waves
    qmeas_kernel<<<grid, block, 0, stream>>>(sre, sim, out);
}

// Round 4
// 113.297 us; speedup vs baseline: 1.0335x; 1.0335x over previous
//
#include <hip/hip_runtime.h>

// QuantumMeasurement: exp[b,q] = sum_i (re^2+im^2)[b,i] * (-1)^{bit_{9-q}(i)}
// Pauli-Z is diagonal: never read the 80 MB observable. Pure streaming
// reduction, 64 MB in, 320 KB out. One 64-lane wave per batch row.
// Grid is fully co-resident (2048 blocks = 256 CU x 8 blocks/CU), so the
// epilogue overlaps other waves' loads and is off the critical path (proven
// by v1->v2 null, +0.2 us).
//
// v4 = v2 with R/I interleaved issue order. v3's nontemporal-load experiment
// REGRESSED (+4.9 us): nt bypasses L2/L3 allocation, and the normal-load
// path was evidently getting real cache hits on the input stream despite the
// harness poison fills. Keep cached loads.

#define BATCH 8192
#define DIM   1024
#define NQ    10

__global__ __launch_bounds__(256, 8) void qmeas_kernel(
    const float* __restrict__ sre,
    const float* __restrict__ sim,
    float* __restrict__ out)
{
    const int row  = (int)((blockIdx.x * blockDim.x + threadIdx.x) >> 6);
    const int lane = (int)(threadIdx.x & 63);
    const int wv   = (int)(threadIdx.x >> 6);   // wave id within block (0..3)

    const float4* __restrict__ rowR = (const float4*)(sre + (size_t)row * DIM);
    const float4* __restrict__ rowI = (const float4*)(sim + (size_t)row * DIM);

    // element index i = 4*(lane + 64*it) + c
    //   bits 0,1 of i = c     -> qubits 9,8  (intra-float4 signed combos)
    //   bits 2..7 of i = lane -> qubits 7..2 (signed WHT butterfly)
    //   bits 8,9 of i = it    -> qubits 1,0  (compile-time signs)

    // 8 cached loads, R/I interleaved: first ACC depends on the two OLDEST
    // loads (vmcnt(6) at first use), all 8 in flight before any use.
    float4 r0 = rowR[lane];       float4 m0 = rowI[lane];
    float4 r1 = rowR[lane + 64];  float4 m1 = rowI[lane + 64];
    float4 r2 = rowR[lane + 128]; float4 m2 = rowI[lane + 128];
    float4 r3 = rowR[lane + 192]; float4 m3 = rowI[lane + 192];

    float tot = 0.f, a8 = 0.f, a9 = 0.f, aq0 = 0.f, aq1 = 0.f;

#define ACC(rr, mm, it) do {                                    \
        float p0 = fmaf(rr.x, rr.x, mm.x * mm.x);               \
        float p1 = fmaf(rr.y, rr.y, mm.y * mm.y);               \
        float p2 = fmaf(rr.z, rr.z, mm.z * mm.z);               \
        float p3 = fmaf(rr.w, rr.w, mm.w * mm.w);               \
        float pa = p0 + p1, pb = p2 + p3;                       \
        float pe = p0 - p1, pf = p2 - p3;                       \
        float ps = pa + pb;                                     \
        a9  += pe + pf;              /* qubit 9: bit0 of i */   \
        a8  += pa - pb;              /* qubit 8: bit1 of i */   \
        tot += ps;                                              \
        aq1 += ((it) & 1) ? -ps : ps; /* qubit 1: bit8 of i */  \
        aq0 += ((it) & 2) ? -ps : ps; /* qubit 0: bit9 of i */  \
    } while (0)

    ACC(r0, m0, 0);
    ACC(r1, m1, 1);
    ACC(r2, m2, 2);
    ACC(r3, m3, 3);
#undef ACC

    // ---- signed Walsh-Hadamard butterfly on tot (6 shuffles total) ----
    // After all 6 levels, lane L = 1<<k holds sum_j (-1)^{bit_k(j)} tot_j,
    // i.e. qubit 7-k (lane bit k is bit k+2 of element index i).
    float s = tot;
#pragma unroll
    for (int k = 0; k < 6; ++k) {
        float y = __shfl_xor(s, 1 << k);
        s = (lane & (1 << k)) ? (y - s) : (s + y);
    }

    // ---- LDS transpose for the 4 plain sums (aq0, aq1, a8, a9) ----
    // write: ds_write_b128, conflict-free (lanes 0..7 cover all 32 banks).
    // read: 16-lane group g sums accumulator g; 2-way aliasing only (free).
    __shared__ float xp[4][64][4];
    xp[wv][lane][0] = aq0;
    xp[wv][lane][1] = aq1;
    xp[wv][lane][2] = a8;
    xp[wv][lane][3] = a9;
    __syncthreads();

    const int g = lane >> 4;      // which accumulator this group reduces
    const int m = lane & 15;
    float v0 = xp[wv][m     ][g];
    float v1 = xp[wv][m + 16][g];
    float v2 = xp[wv][m + 32][g];
    float v3 = xp[wv][m + 48][g];
    float sum4 = (v0 + v1) + (v2 + v3);
#pragma unroll
    for (int d = 1; d < 16; d <<= 1)   // stays within the 16-lane group
        sum4 += __shfl_xor(sum4, d);

    // ---- one predicated wave store: 10 lanes write 10 contiguous floats --
    // WHT lanes 1,2,4,8,16,32 -> qubits 7,6,5,4,3,2
    // group reps 3,19,35,51   -> qubits 0,1,8,9 (avoid WHT lanes)
    int   q   = -1;
    float val = 0.f;
    if      (lane == 1)  { q = 7; val = s; }
    else if (lane == 2)  { q = 6; val = s; }
    else if (lane == 4)  { q = 5; val = s; }
    else if (lane == 8)  { q = 4; val = s; }
    else if (lane == 16) { q = 3; val = s; }
    else if (lane == 32) { q = 2; val = s; }
    else if (lane == 3)  { q = 0; val = sum4; }
    else if (lane == 19) { q = 1; val = sum4; }
    else if (lane == 35) { q = 8; val = sum4; }
    else if (lane == 51) { q = 9; val = sum4; }
    if (q >= 0)
        out[(size_t)row * NQ + q] = val;
}

extern "C" void kernel_launch(void* const* d_in, const int* in_sizes, int n_in,
                              void* d_out, int out_size, void* d_ws, size_t ws_size,
                              hipStream_t stream) {
    const float* sre = (const float*)d_in[0];
    const float* sim = (const float*)d_in[1];
    // d_in[2] (pauli_z_obs) intentionally unused: diagonal signs are analytic.
    float* out = (float*)d_out;

    dim3 grid(BATCH / 4), block(256);   // 4 waves (rows) per block, 8192 waves
    qmeas_kernel<<<grid, block, 0, stream>>>(sre, sim, out);
}